// Round 3
// baseline (54.501 us; speedup 1.0000x reference)
//
#include <hip/hip_runtime.h>
#include <math.h>

#define BB 4
#define NN 512
#define PP 2048
#define EE 32768
#define FH 128
#define DRBF 32
#define INDIM (DRBF + 3*FH)   // 416
#define CUT 4.0f
#define PI_F 3.14159265358979323846f

struct __align__(16) Rec { float dx, dy, dz; unsigned int ap; };

// Zero the output accumulator and the survivor counter (replaces 2 fill nodes).
__global__ __launch_bounds__(256) void init_kernel(float* __restrict__ out, int* __restrict__ cnt) {
  int idx = blockIdx.x * blockDim.x + threadIdx.x;
  if (idx < BB * PP) out[idx] = 0.0f;
  if (idx == 0) *cnt = 0;
}

// Pass 1: compute per-edge displacement/distance, compact survivors (dist < CUTOFF).
__global__ __launch_bounds__(256) void filter_kernel(
    const int* __restrict__ pe,        // (B,E,2) int32: [atom_loc, probe_loc]
    const float* __restrict__ pdisp,   // (B,E,3)
    const float* __restrict__ cell,    // (B,3,3)
    const float* __restrict__ atom_xyz,// (B,N,3)
    const float* __restrict__ probe_xyz,// (B,P,3)
    int* __restrict__ cnt,
    Rec* __restrict__ recs) {
  int e = blockIdx.x * blockDim.x + threadIdx.x;   // grid sized to exactly B*E
  int b = e >> 15;                                 // E = 32768 = 2^15
  int2 ap = ((const int2*)pe)[e];
  float pd0 = pdisp[e*3], pd1 = pdisp[e*3+1], pd2 = pdisp[e*3+2];
  const float* cb = cell + b*9;
  float d0 = pd0*cb[0] + pd1*cb[3] + pd2*cb[6];
  float d1 = pd0*cb[1] + pd1*cb[4] + pd2*cb[7];
  float d2 = pd0*cb[2] + pd1*cb[5] + pd2*cb[8];
  int ag = b*NN + ap.x;
  int pg = b*PP + ap.y;
  float dx = probe_xyz[pg*3]   - (atom_xyz[ag*3]   + d0);
  float dy = probe_xyz[pg*3+1] - (atom_xyz[ag*3+1] + d1);
  float dz = probe_xyz[pg*3+2] - (atom_xyz[ag*3+2] + d2);
  float dist2 = dx*dx + dy*dy + dz*dz;
  if (dist2 < CUT*CUT) {
    int i = atomicAdd(cnt, 1);
    Rec r; r.dx = dx; r.dy = dy; r.dz = dz;
    r.ap = ((unsigned)ag << 16) | (unsigned)pg;
    recs[i] = r;
  }
}

// Pass 2: each wave processes 4 edges. Weight streams are register-blocked in
// groups of 16 rows with explicit A/B double-buffering so the 16 loads of the
// next group are in flight while the current group's FMAs run (breaks the
// one-round-trip-per-k latency chain that cost ~41us in R1/R2).
__global__ __launch_bounds__(256) void mlp_kernel(
    const Rec* __restrict__ recs, const int* __restrict__ cnt,
    const float* __restrict__ S,   // (B*N, 128)
    const float* __restrict__ V,   // (B*N, 3, 128)
    const float* __restrict__ W1, const float* __restrict__ b1,
    const float* __restrict__ W2, const float* __restrict__ b2,
    const float* __restrict__ W3, const float* __restrict__ b3,
    float* __restrict__ out) {
  __shared__ float hbuf[4][4][INDIM];   // [wave][edge][feature] = 26.6 KB
  const int lane = threadIdx.x & 63;
  const int wave = threadIdx.x >> 6;
  const int wgl = wave * gridDim.x + blockIdx.x;   // wave-major: spread over CUs
  const int nw  = gridDim.x * 4;
  const int n   = *cnt;
  const int nbatch = (n + 3) >> 2;
  float (*h)[INDIM] = hbuf[wave];
  const float2* W1f2 = (const float2*)W1;
  const float2* Vf2  = (const float2*)V;
  const float2* Sf2  = (const float2*)S;

  for (int bt = wgl; bt < nbatch; bt += nw) {
    const int e0 = bt << 2;
    float cwv[4]; unsigned pv[4];

    // ---- Gather: batch the 4 recs loads, then per-edge feature builds ----
    Rec r[4];
    #pragma unroll
    for (int j = 0; j < 4; ++j) {
      int e = e0 + j;
      if (e < n) r[j] = recs[e];
      else { r[j].dx = 1.0f; r[j].dy = 0.0f; r[j].dz = 0.0f; r[j].ap = 0x0000FFFFu; }
    }
    #pragma unroll
    for (int j = 0; j < 4; ++j) {
      unsigned a = r[j].ap >> 16;
      pv[j] = r[j].ap & 0xFFFFu;
      float d = sqrtf(r[j].dx*r[j].dx + r[j].dy*r[j].dy + r[j].dz*r[j].dz);
      float inv = 1.0f / (d + 1e-8f);
      float rh0 = r[j].dx*inv, rh1 = r[j].dy*inv, rh2 = r[j].dz*inv;
      cwv[j] = 0.5f * (cosf((PI_F/CUT) * d) + 1.0f);
      if (lane < DRBF) h[j][lane] = sinf(d * (float)(lane+1) * (PI_F/CUT)) / d;
      float2 v0 = Vf2[(a*3+0)*64 + lane];
      float2 v1 = Vf2[(a*3+1)*64 + lane];
      float2 v2 = Vf2[(a*3+2)*64 + lane];
      float2 sj = Sf2[a*64 + lane];
      float2 q;  q.x  = v0.x*rh0 + v1.x*rh1 + v2.x*rh2;
                 q.y  = v0.y*rh0 + v1.y*rh1 + v2.y*rh2;
      float2 nv; nv.x = sqrtf(v0.x*v0.x + v1.x*v1.x + v2.x*v2.x);
                 nv.y = sqrtf(v0.y*v0.y + v1.y*v1.y + v2.y*v2.y);
      *(float2*)&h[j][DRBF        + 2*lane] = q;
      *(float2*)&h[j][DRBF +   FH + 2*lane] = nv;
      *(float2*)&h[j][DRBF + 2*FH + 2*lane] = sj;
    }
    __threadfence_block();

    // ---- Layer 1: lane owns features {2l,2l+1}; 26 groups of 16 rows ----
    const float2* Wp = W1f2 + lane;
    float2 wA[16], wB[16];
    #pragma unroll
    for (int t = 0; t < 16; ++t) wA[t] = Wp[t*64];           // group 0 in flight
    float2 bb = ((const float2*)b1)[lane];
    float a0[4], a1[4];
    #pragma unroll
    for (int j = 0; j < 4; ++j) { a0[j] = bb.x; a1[j] = bb.y; }

    for (int gp = 0; gp < 13; ++gp) {          // 13 pairs x 32 rows = 416
      const int kb = gp * 32;
      #pragma unroll
      for (int t = 0; t < 16; ++t) wB[t] = Wp[(kb + 16 + t)*64];
      #pragma unroll
      for (int j = 0; j < 4; ++j) {
        #pragma unroll
        for (int t4 = 0; t4 < 4; ++t4) {
          float4 hv = *(const float4*)&h[j][kb + 4*t4];
          a0[j] = fmaf(hv.x, wA[4*t4+0].x, a0[j]); a1[j] = fmaf(hv.x, wA[4*t4+0].y, a1[j]);
          a0[j] = fmaf(hv.y, wA[4*t4+1].x, a0[j]); a1[j] = fmaf(hv.y, wA[4*t4+1].y, a1[j]);
          a0[j] = fmaf(hv.z, wA[4*t4+2].x, a0[j]); a1[j] = fmaf(hv.z, wA[4*t4+2].y, a1[j]);
          a0[j] = fmaf(hv.w, wA[4*t4+3].x, a0[j]); a1[j] = fmaf(hv.w, wA[4*t4+3].y, a1[j]);
        }
      }
      if (gp < 12) {
        #pragma unroll
        for (int t = 0; t < 16; ++t) wA[t] = Wp[(kb + 32 + t)*64];
      }
      #pragma unroll
      for (int j = 0; j < 4; ++j) {
        #pragma unroll
        for (int t4 = 0; t4 < 4; ++t4) {
          float4 hv = *(const float4*)&h[j][kb + 16 + 4*t4];
          a0[j] = fmaf(hv.x, wB[4*t4+0].x, a0[j]); a1[j] = fmaf(hv.x, wB[4*t4+0].y, a1[j]);
          a0[j] = fmaf(hv.y, wB[4*t4+1].x, a0[j]); a1[j] = fmaf(hv.y, wB[4*t4+1].y, a1[j]);
          a0[j] = fmaf(hv.z, wB[4*t4+2].x, a0[j]); a1[j] = fmaf(hv.z, wB[4*t4+2].y, a1[j]);
          a0[j] = fmaf(hv.w, wB[4*t4+3].x, a0[j]); a1[j] = fmaf(hv.w, wB[4*t4+3].y, a1[j]);
        }
      }
    }
    __threadfence_block();
    #pragma unroll
    for (int j = 0; j < 4; ++j) {
      float2 hv;
      hv.x = a0[j] / (1.0f + __expf(-a0[j]));
      hv.y = a1[j] / (1.0f + __expf(-a1[j]));
      *(float2*)&h[j][2*lane] = hv;
    }
    __threadfence_block();

    // ---- Layer 2: lane owns output feature `lane`; 8 groups of 16 rows ----
    const float* W2p = W2 + lane;
    float w2A[16], w2B[16];
    #pragma unroll
    for (int t = 0; t < 16; ++t) w2A[t] = W2p[t*64];
    float b2v = b2[lane];
    float acc2[4];
    #pragma unroll
    for (int j = 0; j < 4; ++j) acc2[j] = b2v;

    for (int gp = 0; gp < 4; ++gp) {           // 4 pairs x 32 rows = 128
      const int kb = gp * 32;
      #pragma unroll
      for (int t = 0; t < 16; ++t) w2B[t] = W2p[(kb + 16 + t)*64];
      #pragma unroll
      for (int j = 0; j < 4; ++j) {
        #pragma unroll
        for (int t4 = 0; t4 < 4; ++t4) {
          float4 hv = *(const float4*)&h[j][kb + 4*t4];
          acc2[j] = fmaf(hv.x, w2A[4*t4+0], acc2[j]);
          acc2[j] = fmaf(hv.y, w2A[4*t4+1], acc2[j]);
          acc2[j] = fmaf(hv.z, w2A[4*t4+2], acc2[j]);
          acc2[j] = fmaf(hv.w, w2A[4*t4+3], acc2[j]);
        }
      }
      if (gp < 3) {
        #pragma unroll
        for (int t = 0; t < 16; ++t) w2A[t] = W2p[(kb + 32 + t)*64];
      }
      #pragma unroll
      for (int j = 0; j < 4; ++j) {
        #pragma unroll
        for (int t4 = 0; t4 < 4; ++t4) {
          float4 hv = *(const float4*)&h[j][kb + 16 + 4*t4];
          acc2[j] = fmaf(hv.x, w2B[4*t4+0], acc2[j]);
          acc2[j] = fmaf(hv.y, w2B[4*t4+1], acc2[j]);
          acc2[j] = fmaf(hv.z, w2B[4*t4+2], acc2[j]);
          acc2[j] = fmaf(hv.w, w2B[4*t4+3], acc2[j]);
        }
      }
    }

    // ---- Layer 3: dot over 64 lanes + cutoff weight + scatter-add ----
    float w3  = W3[lane];
    float b3v = b3[0];
    #pragma unroll
    for (int j = 0; j < 4; ++j) {
      float h2 = acc2[j] / (1.0f + __expf(-acc2[j]));
      float rs = h2 * w3;
      #pragma unroll
      for (int off = 32; off; off >>= 1) rs += __shfl_xor(rs, off, 64);
      if (lane == 0 && pv[j] != 0xFFFFu) {
        atomicAdd(&out[pv[j]], (rs + b3v) * cwv[j]);
      }
    }
  }
}

extern "C" void kernel_launch(void* const* d_in, const int* in_sizes, int n_in,
                              void* d_out, int out_size, void* d_ws, size_t ws_size,
                              hipStream_t stream) {
  const float* S         = (const float*)d_in[0];
  const float* V         = (const float*)d_in[1];
  const float* atom_xyz  = (const float*)d_in[2];
  const float* probe_xyz = (const float*)d_in[3];
  const float* cell      = (const float*)d_in[4];
  const float* pdisp     = (const float*)d_in[5];
  const float* W1        = (const float*)d_in[6];
  const float* b1        = (const float*)d_in[7];
  const float* W2        = (const float*)d_in[8];
  const float* b2        = (const float*)d_in[9];
  const float* W3        = (const float*)d_in[10];
  const float* b3        = (const float*)d_in[11];
  const int*   pe        = (const int*)d_in[12];
  float* out = (float*)d_out;

  int* cnt  = (int*)d_ws;
  Rec* recs = (Rec*)((char*)d_ws + 16);

  init_kernel<<<32, 256, 0, stream>>>(out, cnt);
  filter_kernel<<<BB*EE/256, 256, 0, stream>>>(pe, pdisp, cell, atom_xyz, probe_xyz, cnt, recs);
  mlp_kernel<<<256, 256, 0, stream>>>(recs, cnt, S, V, W1, b1, W2, b2, W3, b3, out);
}

// Round 4
// 39.923 us; speedup vs baseline: 1.3652x; 1.3652x over previous
//
#include <hip/hip_runtime.h>
#include <math.h>

#define BB 4
#define NN 512
#define PP 2048
#define EE 32768
#define FH 128
#define DRBF 32
#define INDIM 416
#define CUT 4.0f
#define PI_F 3.14159265358979323846f
#define HSTR 420   // padded h row stride (floats): 420%32=4 -> edges land on distinct banks

struct __align__(16) Rec { float dx, dy, dz; unsigned int ap; };

__global__ __launch_bounds__(256) void init_kernel(float* __restrict__ out, int* __restrict__ cnt) {
  int idx = blockIdx.x * blockDim.x + threadIdx.x;
  if (idx < BB * PP) out[idx] = 0.0f;
  if (idx == 0) *cnt = 0;
}

// Pass 1: per-edge displacement/distance, compact survivors (dist < CUTOFF).
__global__ __launch_bounds__(256) void filter_kernel(
    const int* __restrict__ pe, const float* __restrict__ pdisp,
    const float* __restrict__ cell, const float* __restrict__ atom_xyz,
    const float* __restrict__ probe_xyz, int* __restrict__ cnt, Rec* __restrict__ recs) {
  int e = blockIdx.x * blockDim.x + threadIdx.x;   // grid covers exactly B*E
  int b = e >> 15;
  int2 ap = ((const int2*)pe)[e];
  float pd0 = pdisp[e*3], pd1 = pdisp[e*3+1], pd2 = pdisp[e*3+2];
  const float* cb = cell + b*9;
  float d0 = pd0*cb[0] + pd1*cb[3] + pd2*cb[6];
  float d1 = pd0*cb[1] + pd1*cb[4] + pd2*cb[7];
  float d2 = pd0*cb[2] + pd1*cb[5] + pd2*cb[8];
  int ag = b*NN + ap.x;
  int pg = b*PP + ap.y;
  float dx = probe_xyz[pg*3]   - (atom_xyz[ag*3]   + d0);
  float dy = probe_xyz[pg*3+1] - (atom_xyz[ag*3+1] + d1);
  float dz = probe_xyz[pg*3+2] - (atom_xyz[ag*3+2] + d2);
  float dist2 = dx*dx + dy*dy + dz*dz;
  if (dist2 < CUT*CUT) {
    int i = atomicAdd(cnt, 1);
    Rec r; r.dx = dx; r.dy = dy; r.dz = dz;
    r.ap = ((unsigned)ag << 16) | (unsigned)pg;
    recs[i] = r;
  }
}

// Pass 2: block of 4 waves handles 4 edges. Weights stream through
// double-buffered LDS (32KB chunks); stage loads issued before each chunk's
// compute (T14) so L2 latency hides under the FMAs. Thread (e=lane&3,
// fo=wave*16+lane>>2) -> each weight word read once per block (broadcast).
__global__ __launch_bounds__(256) void mlp_kernel(
    const Rec* __restrict__ recs, const int* __restrict__ cnt,
    const float* __restrict__ S, const float* __restrict__ V,
    const float* __restrict__ W1, const float* __restrict__ b1,
    const float* __restrict__ W2, const float* __restrict__ b2,
    const float* __restrict__ W3, const float* __restrict__ b3,
    float* __restrict__ out) {
  __shared__ float bufA[64*FH];    // 32KB
  __shared__ float bufB[64*FH];    // 32KB
  __shared__ float hS[4][HSTR];    // 6.7KB
  __shared__ float partS[4][4];
  __shared__ float cwS[4];
  __shared__ unsigned pS[4];

  const int tid  = threadIdx.x;
  const int lane = tid & 63;
  const int wave = tid >> 6;
  const int e    = lane & 3;                 // edge within block
  const int fo   = (wave << 4) + (lane >> 2); // feature-pair (L1) / out-feat (L2)

  const int n = *cnt;
  const float2* Vf2 = (const float2*)V;
  const float2* Sf2 = (const float2*)S;

  // loop-invariant small params
  float2 b1v = ((const float2*)b1)[fo];
  float  b2v = b2[fo];
  float  w3v = W3[fo];
  float  b3v = b3[0];

  for (int bt = blockIdx.x; bt * 4 < n; bt += gridDim.x) {
    __syncthreads();   // protect LDS reuse across bt iterations

    // ---- gather: wave w builds h for edge bt*4+w ----
    int eg = bt * 4 + wave;
    Rec r;
    unsigned p;
    if (eg < n) { r = recs[eg]; p = r.ap & 0xFFFFu; }
    else        { r.dx = 1.0f; r.dy = 0.0f; r.dz = 0.0f; r.ap = 0u; p = 0xFFFFu; }
    unsigned a = r.ap >> 16;
    float2 v0 = Vf2[(a*3+0)*64 + lane];
    float2 v1 = Vf2[(a*3+1)*64 + lane];
    float2 v2 = Vf2[(a*3+2)*64 + lane];
    float2 sj = Sf2[a*64 + lane];

    // issue chunk-0 stage loads (in flight while gather math runs)
    float4 st[8];
    {
      const float4* gs = (const float4*)W1;
      #pragma unroll
      for (int i = 0; i < 8; ++i) st[i] = gs[i*256 + tid];
    }

    float d = sqrtf(r.dx*r.dx + r.dy*r.dy + r.dz*r.dz);
    float inv = 1.0f / (d + 1e-8f);
    float rh0 = r.dx*inv, rh1 = r.dy*inv, rh2 = r.dz*inv;
    float cw = 0.5f * (cosf((PI_F/CUT) * d) + 1.0f);
    if (lane < DRBF) hS[wave][lane] = sinf(d * (float)(lane+1) * (PI_F/CUT)) / d;
    float2 q;  q.x  = v0.x*rh0 + v1.x*rh1 + v2.x*rh2;
               q.y  = v0.y*rh0 + v1.y*rh1 + v2.y*rh2;
    float2 nv; nv.x = sqrtf(v0.x*v0.x + v1.x*v1.x + v2.x*v2.x);
               nv.y = sqrtf(v0.y*v0.y + v1.y*v1.y + v2.y*v2.y);
    *(float2*)&hS[wave][DRBF        + 2*lane] = q;
    *(float2*)&hS[wave][DRBF +   FH + 2*lane] = nv;
    *(float2*)&hS[wave][DRBF + 2*FH + 2*lane] = sj;
    if (lane == 0) { cwS[wave] = cw; pS[wave] = p; }

    // write chunk 0 into bufA
    #pragma unroll
    for (int i = 0; i < 8; ++i) *(float4*)&bufA[(i*256 + tid)*4] = st[i];
    __syncthreads();

    // ---- layer 1 over 7 chunks (64,64,64,64,64,64,32 rows) ----
    float acc0 = b1v.x, acc1 = b1v.y;
    #pragma unroll
    for (int c = 0; c < 7; ++c) {
      // issue stage for next chunk (c+1): chunks 1..6 of W1, then W2 as "chunk 7"
      float4 st2[8];
      const int nld = (c == 5) ? 4 : 8;
      {
        const float4* gs = (c < 6) ? (const float4*)(W1 + (c+1)*64*FH)
                                   : (const float4*)W2;
        #pragma unroll
        for (int i = 0; i < 8; ++i) if (i < nld) st2[i] = gs[i*256 + tid];
      }
      // compute chunk c from buf[c&1]
      const float* wb = (c & 1) ? bufB : bufA;
      const int rows = (c < 6) ? 64 : 32;
      const float* hrow = &hS[e][c*64];
      #pragma unroll 4
      for (int k4 = 0; k4 < rows/4; ++k4) {
        float4 hv = *(const float4*)&hrow[4*k4];
        const float* wr = &wb[(4*k4)*FH + 2*fo];
        float2 w0 = *(const float2*)&wr[0];
        float2 w1 = *(const float2*)&wr[FH];
        float2 w2 = *(const float2*)&wr[2*FH];
        float2 w3r= *(const float2*)&wr[3*FH];
        acc0 = fmaf(hv.x, w0.x, acc0); acc1 = fmaf(hv.x, w0.y, acc1);
        acc0 = fmaf(hv.y, w1.x, acc0); acc1 = fmaf(hv.y, w1.y, acc1);
        acc0 = fmaf(hv.z, w2.x, acc0); acc1 = fmaf(hv.z, w2.y, acc1);
        acc0 = fmaf(hv.w, w3r.x, acc0); acc1 = fmaf(hv.w, w3r.y, acc1);
      }
      // write staged chunk c+1 into buf[(c+1)&1]
      float* db = ((c+1) & 1) ? bufB : bufA;
      #pragma unroll
      for (int i = 0; i < 8; ++i) if (i < nld) *(float4*)&db[(i*256 + tid)*4] = st2[i];
      __syncthreads();
    }

    // silu -> h2 (overwrite hS[e][0..127]); bufB now holds W2
    float h1a = acc0 / (1.0f + __expf(-acc0));
    float h1b = acc1 / (1.0f + __expf(-acc1));
    *(float2*)&hS[e][2*fo] = make_float2(h1a, h1b);
    __syncthreads();

    // ---- layer 2: out-feat fo of edge e ----
    float acc2 = b2v;
    #pragma unroll 8
    for (int k4 = 0; k4 < 32; ++k4) {
      float4 hv = *(const float4*)&hS[e][4*k4];
      acc2 = fmaf(hv.x, bufB[(4*k4+0)*64 + fo], acc2);
      acc2 = fmaf(hv.y, bufB[(4*k4+1)*64 + fo], acc2);
      acc2 = fmaf(hv.z, bufB[(4*k4+2)*64 + fo], acc2);
      acc2 = fmaf(hv.w, bufB[(4*k4+3)*64 + fo], acc2);
    }
    float h2 = acc2 / (1.0f + __expf(-acc2));

    // ---- layer 3: reduce over the 16 lanes sharing edge e, then over waves ----
    float rs = h2 * w3v;
    rs += __shfl_xor(rs, 4, 64);
    rs += __shfl_xor(rs, 8, 64);
    rs += __shfl_xor(rs, 16, 64);
    rs += __shfl_xor(rs, 32, 64);
    if (lane < 4) partS[wave][lane] = rs;
    __syncthreads();
    if (wave == 0 && lane < 4) {
      unsigned pp = pS[lane];
      if (pp != 0xFFFFu) {
        float m = partS[0][lane] + partS[1][lane] + partS[2][lane] + partS[3][lane] + b3v;
        atomicAdd(&out[pp], m * cwS[lane]);
      }
    }
  }
}

extern "C" void kernel_launch(void* const* d_in, const int* in_sizes, int n_in,
                              void* d_out, int out_size, void* d_ws, size_t ws_size,
                              hipStream_t stream) {
  const float* S         = (const float*)d_in[0];
  const float* V         = (const float*)d_in[1];
  const float* atom_xyz  = (const float*)d_in[2];
  const float* probe_xyz = (const float*)d_in[3];
  const float* cell      = (const float*)d_in[4];
  const float* pdisp     = (const float*)d_in[5];
  const float* W1        = (const float*)d_in[6];
  const float* b1        = (const float*)d_in[7];
  const float* W2        = (const float*)d_in[8];
  const float* b2        = (const float*)d_in[9];
  const float* W3        = (const float*)d_in[10];
  const float* b3        = (const float*)d_in[11];
  const int*   pe        = (const int*)d_in[12];
  float* out = (float*)d_out;

  int* cnt  = (int*)d_ws;
  Rec* recs = (Rec*)((char*)d_ws + 16);

  init_kernel<<<32, 256, 0, stream>>>(out, cnt);
  filter_kernel<<<BB*EE/256, 256, 0, stream>>>(pe, pdisp, cell, atom_xyz, probe_xyz, cnt, recs);
  mlp_kernel<<<512, 256, 0, stream>>>(recs, cnt, S, V, W1, b1, W2, b2, W3, b3, out);
}